// Round 1
// 326.400 us; speedup vs baseline: 1.0016x; 1.0016x over previous
//
#include <hip/hip_runtime.h>
#include <hip/hip_bf16.h>
#include <math.h>

// Problem constants (from reference)
#define NN 50000
#define EE 800000
#define IN_CH 128
#define HH 4
#define CC 64
#define GG 64
#define HC 256   // H*C
#define SLOPE 0.2f

typedef short bf16x8 __attribute__((ext_vector_type(8)));   // 8 bf16 (4 VGPRs)
typedef float f32x4  __attribute__((ext_vector_type(4)));   // 4 fp32 acc

__device__ inline ushort f2bf(float f) {
    union { __hip_bfloat16 h; ushort u; } c;
    c.h = __float2bfloat16(f);
    return c.u;
}
__device__ inline float bflo(uint u) {            // low bf16 -> f32 (exact)
    union { uint u; float f; } c; c.u = u << 16; return c.f;
}
__device__ inline float bfhi(uint u) {            // high bf16 -> f32 (exact)
    union { uint u; float f; } c; c.u = u & 0xffff0000u; return c.f;
}

// ---------------- CSR build ----------------

__global__ void init_deg_kernel(int* __restrict__ deg, int n) {
    int i = blockIdx.x * blockDim.x + threadIdx.x;
    if (i < n) deg[i] = 1;  // self loop
}

__global__ void count_kernel(const int* __restrict__ ei, int* __restrict__ deg, int E) {
    int i = blockIdx.x * blockDim.x + threadIdx.x;
    if (i < E) atomicAdd(&deg[ei[E + i]], 1);  // row 1 = dst
}

__global__ __launch_bounds__(256) void scanA_kernel(const int* __restrict__ deg,
                                                    int* __restrict__ off,
                                                    int* __restrict__ bsum, int n) {
    int t = threadIdx.x;
    int lane = t & 63, wid = t >> 6;
    int idx = blockIdx.x * 1024 + t * 4;
    int v[4];
    int s = 0;
    #pragma unroll
    for (int k = 0; k < 4; ++k) { v[k] = (idx + k < n) ? deg[idx + k] : 0; s += v[k]; }
    int incl = s;
    #pragma unroll
    for (int d = 1; d < 64; d <<= 1) { int tt = __shfl_up(incl, d, 64); if (lane >= d) incl += tt; }
    __shared__ int ws[4];
    if (lane == 63) ws[wid] = incl;
    __syncthreads();
    int carry = 0;
    for (int w = 0; w < wid; ++w) carry += ws[w];
    int excl = incl - s + carry;
    #pragma unroll
    for (int k = 0; k < 4; ++k) { if (idx + k < n) off[idx + k] = excl; excl += v[k]; }
    if (t == 255) bsum[blockIdx.x] = carry + incl;
}

__global__ void scanB_kernel(int* __restrict__ bsum, int nb, int* __restrict__ off_n) {
    int lane = threadIdx.x;
    int v = (lane < nb) ? bsum[lane] : 0;
    int incl = v;
    #pragma unroll
    for (int d = 1; d < 64; d <<= 1) { int t = __shfl_up(incl, d, 64); if (lane >= d) incl += t; }
    if (lane < nb) bsum[lane] = incl - v;
    if (lane == nb - 1) *off_n = incl;
}

__global__ void scanC_kernel(int* __restrict__ off, int* __restrict__ cur,
                             const int* __restrict__ bsum, int n) {
    int i = blockIdx.x * blockDim.x + threadIdx.x;
    if (i < n) { int v = off[i] + bsum[i >> 10]; off[i] = v; cur[i] = v; }
}

__global__ void scatter_kernel(const int* __restrict__ ei, int* __restrict__ cur,
                               int* __restrict__ csrs, int E, int n) {
    int i = blockIdx.x * blockDim.x + threadIdx.x;
    if (i >= E + n) return;
    int s, d;
    if (i < E) { s = ei[i]; d = ei[E + i]; }
    else       { s = i - E; d = s; }        // self loop
    int pos = atomicAdd(&cur[d], 1);
    csrs[pos] = s;
}

// ---------------- weight pre-transpose/convert ----------------
// B [K][256] f32 -> Bt [K/32][256][32] bf16 (k-tiled, transposed)

__global__ __launch_bounds__(256) void convert_w_kernel(const float* __restrict__ B,
                                                        ushort* __restrict__ Bt, int K) {
    __shared__ float tile[32][33];
    int kt = blockIdx.x;
    int n0 = blockIdx.y * 32;
    int tx = threadIdx.x & 31, ty = threadIdx.x >> 5;  // 32 x 8
    #pragma unroll
    for (int r = ty; r < 32; r += 8)
        tile[r][tx] = B[(size_t)(kt * 32 + r) * 256 + n0 + tx];
    __syncthreads();
    #pragma unroll
    for (int r = ty; r < 32; r += 8)
        Bt[((size_t)kt * 256 + n0 + r) * 32 + tx] = f2bf(tile[tx][r]);
}

// ---------------- fused MFMA GEMM + alpha epilogue ----------------
// H2[M,256] (bf16) = A[M,K] @ W ; as_/ad_[M,4] = per-head dots with a_src/a_dst.

template <int K, bool A_BF16>
__global__ __launch_bounds__(256) void mfma_gemm_fused(const void* __restrict__ Ap,
                                                       const ushort* __restrict__ Bt,
                                                       ushort* __restrict__ H2,
                                                       float* __restrict__ as_,
                                                       float* __restrict__ ad_,
                                                       const float* __restrict__ a_src,
                                                       const float* __restrict__ a_dst,
                                                       int M) {
    __shared__ __align__(16) ushort As[64 * 32];    // 4 KB
    __shared__ __align__(16) ushort Bs[256 * 32];   // 16 KB
    int tid = threadIdx.x;
    int wave = tid >> 6, lane = tid & 63;
    int bm = blockIdx.x * 64;

    f32x4 acc[4][4] = {{}};

    for (int k0 = 0; k0 < K; k0 += 32) {
        // ---- stage A: thread t -> row t>>2, slot t&3 (8 k's = 16B bf16)
        {
            int row = tid >> 2, sl = tid & 3;
            int gr = bm + row;
            uint4 q = {0u, 0u, 0u, 0u};
            if (gr < M) {
                if constexpr (A_BF16) {
                    q = *reinterpret_cast<const uint4*>((const ushort*)Ap + (size_t)gr * K + k0 + sl * 8);
                } else {
                    const float* ap = (const float*)Ap + (size_t)gr * K + k0 + sl * 8;
                    float4 f0 = *reinterpret_cast<const float4*>(ap);
                    float4 f1 = *reinterpret_cast<const float4*>(ap + 4);
                    q.x = (uint)f2bf(f0.x) | ((uint)f2bf(f0.y) << 16);
                    q.y = (uint)f2bf(f0.z) | ((uint)f2bf(f0.w) << 16);
                    q.z = (uint)f2bf(f1.x) | ((uint)f2bf(f1.y) << 16);
                    q.w = (uint)f2bf(f1.z) | ((uint)f2bf(f1.w) << 16);
                }
            }
            int ssl = sl ^ ((row >> 1) & 3);
            *reinterpret_cast<uint4*>(&As[row * 32 + ssl * 8]) = q;
        }
        // ---- stage B: full 256n x 32k tile = 1024 x 16B chunks; 4 per thread
        {
            const ushort* bt = Bt + (size_t)(k0 >> 5) * (256 * 32);
            #pragma unroll
            for (int cI = 0; cI < 4; ++cI) {
                int idx = cI * 256 + tid;            // 0..1023
                uint4 v = *reinterpret_cast<const uint4*>(bt + idx * 8);
                int n = idx >> 2, sl = idx & 3;
                int ssl = sl ^ ((n >> 1) & 3);
                *reinterpret_cast<uint4*>(&Bs[n * 32 + ssl * 8]) = v;
            }
        }
        __syncthreads();

        int r16 = lane & 15, kg = lane >> 4;
        bf16x8 af[4], bfr[4];
        #pragma unroll
        for (int mi = 0; mi < 4; ++mi) {
            int row = mi * 16 + r16;
            int ssl = kg ^ ((row >> 1) & 3);
            af[mi] = *reinterpret_cast<const bf16x8*>(&As[row * 32 + ssl * 8]);
        }
        #pragma unroll
        for (int ni = 0; ni < 4; ++ni) {
            int n = wave * 64 + ni * 16 + r16;
            int ssl = kg ^ ((n >> 1) & 3);
            bfr[ni] = *reinterpret_cast<const bf16x8*>(&Bs[n * 32 + ssl * 8]);
        }
        #pragma unroll
        for (int mi = 0; mi < 4; ++mi)
            #pragma unroll
            for (int ni = 0; ni < 4; ++ni)
                acc[mi][ni] = __builtin_amdgcn_mfma_f32_16x16x32_bf16(af[mi], bfr[ni], acc[mi][ni], 0, 0, 0);
        __syncthreads();
    }

    // ---- epilogue: bf16 store + fused per-head alpha dots ----
    // C/D layout: col = lane&15, row = (lane>>4)*4 + reg  [m89-verified]
    int r16 = lane & 15, rg = lane >> 4;
    float asv[4], adv[4];
    #pragma unroll
    for (int ni = 0; ni < 4; ++ni) {
        asv[ni] = a_src[wave * 64 + ni * 16 + r16];
        adv[ni] = a_dst[wave * 64 + ni * 16 + r16];
    }
    #pragma unroll
    for (int mi = 0; mi < 4; ++mi) {
        #pragma unroll
        for (int r = 0; r < 4; ++r) {
            int row = bm + mi * 16 + rg * 4 + r;
            float ps = 0.f, pd = 0.f;
            if (row < M) {
                #pragma unroll
                for (int ni = 0; ni < 4; ++ni) {
                    float v = acc[mi][ni][r];
                    H2[(size_t)row * HC + wave * 64 + ni * 16 + r16] = f2bf(v);
                    ps += v * asv[ni];
                    pd += v * adv[ni];
                }
            }
            #pragma unroll
            for (int o = 1; o < 16; o <<= 1) {
                ps += __shfl_xor(ps, o, 64);
                pd += __shfl_xor(pd, o, 64);
            }
            if (row < M && r16 == 0) {
                as_[row * HH + wave] = ps;
                ad_[row * HH + wave] = pd;
            }
        }
    }
}

// ---------------- aggregation v6: wave-per-dst, pair-edge dwordx4 gather ----------------
// wave w of block handles dst = blockIdx.x*4 + w, ALL 4 heads at once.
// softmax: lane = (es, hh) = 16 edge-slots x 4 heads; for deg<=64 a SINGLE pass
//          caches e in 4 regs (one global max + one sum reduction, as_ read once).
// gather:  lane = (ep, cl) = edge-parity x 32 channel-groups; each iteration
//          loads TWO edges' rows as dwordx4 (16B/lane, 1KB/wave) -> 2x MLP vs v5.
//          Parity halves combined with 4 shfl_xor(32) at the end.
// No __syncthreads: each wave uses its own LDS slice.

template <bool OUT_BF16>
__global__ __launch_bounds__(256) void aggregate6_kernel(const ushort* __restrict__ h2,
                                                         const float* __restrict__ as_,
                                                         const float* __restrict__ ad_,
                                                         const int* __restrict__ off,
                                                         const int* __restrict__ csrs,
                                                         const float* __restrict__ bias,
                                                         void* __restrict__ outp, int n) {
    int w = threadIdx.x >> 6, lane = threadIdx.x & 63;
    int dst = blockIdx.x * 4 + w;
    if (dst >= n) return;
    int es = lane >> 2, hh = lane & 3;     // softmax mapping
    int ep = lane >> 5, cl = lane & 31;    // gather: edge parity, 8-channel group
    int hsel = cl >> 3;                    // head owning this lane's channels

    __shared__ float s_alpha[4][64][4];    // [wave][edge][head]
    __shared__ int   s_row[4][64];         // [wave][edge] byte offset of h2 row

    int beg = off[dst], deg = off[dst + 1] - beg;
    float ad = ad_[dst * HH + hh];

    float acc[8] = {};
    const char* hb = (const char*)h2 + cl * 16;   // lane's 8-channel (16B) slice

    int ntile = (deg + 15) >> 4;

    if (ntile <= 4) {
        // ---- single-pass softmax over up to 64 edges (e cached in regs) ----
        float ew[4]; int sw[4];
        float lm = -INFINITY;
        #pragma unroll
        for (int t = 0; t < 4; ++t) {
            int j = t * 16 + es;
            float e = -INFINITY; int s = 0;
            if (t < ntile && j < deg) {
                s = csrs[beg + j];
                e = as_[s * HH + hh] + ad;
                e = e > 0.f ? e : SLOPE * e;
            }
            ew[t] = e; sw[t] = s;
            lm = fmaxf(lm, e);
        }
        #pragma unroll
        for (int o = 4; o < 64; o <<= 1) lm = fmaxf(lm, __shfl_xor(lm, o, 64));
        float den = 0.f;
        #pragma unroll
        for (int t = 0; t < 4; ++t) {
            float wgt = __expf(ew[t] - lm);   // exp(-inf - finite) = 0 for invalid
            ew[t] = wgt; den += wgt;
        }
        #pragma unroll
        for (int o = 4; o < 64; o <<= 1) den += __shfl_xor(den, o, 64);
        float invden = 1.f / den;
        #pragma unroll
        for (int t = 0; t < 4; ++t) {
            int j = t * 16 + es;
            if (t < ntile && j < deg) {
                s_alpha[w][j][hh] = ew[t] * invden;
                if (hh == 0) s_row[w][j] = sw[t] * (HC * 2);
            }
        }
        // ---- pair-edge gather ----
        #pragma unroll 2
        for (int jj = 0; jj < deg; jj += 2) {
            int j = jj + ep;
            int jc = j < deg ? j : jj;
            float a = j < deg ? s_alpha[w][j][hsel] : 0.f;
            int ro = s_row[w][jc];
            const uint4 v = *reinterpret_cast<const uint4*>(hb + ro);
            acc[0] += a * bflo(v.x);
            acc[1] += a * bfhi(v.x);
            acc[2] += a * bflo(v.y);
            acc[3] += a * bfhi(v.y);
            acc[4] += a * bflo(v.z);
            acc[5] += a * bfhi(v.z);
            acc[6] += a * bflo(v.w);
            acc[7] += a * bfhi(v.w);
        }
    } else {
        // ---- fallback deg > 64: online 2-pass over 16-edge tiles (rare) ----
        float m = -INFINITY, den = 0.f;
        for (int j0 = 0; j0 < deg; j0 += 16) {
            int j = j0 + es;
            float e = -INFINITY;
            if (j < deg) {
                int s = csrs[beg + j];
                e = as_[s * HH + hh] + ad;
                e = e > 0.f ? e : SLOPE * e;
            }
            float cm = e;
            #pragma unroll
            for (int o = 4; o < 64; o <<= 1) cm = fmaxf(cm, __shfl_xor(cm, o, 64));
            float nm = fmaxf(m, cm);
            float wgt = (j < deg) ? __expf(e - nm) : 0.f;
            #pragma unroll
            for (int o = 4; o < 64; o <<= 1) wgt += __shfl_xor(wgt, o, 64);
            den = den * __expf(m - nm) + wgt;
            m = nm;
        }
        float invden = 1.f / den;
        for (int j0 = 0; j0 < deg; j0 += 16) {
            int tl = min(16, deg - j0);
            int j = j0 + es;
            if (j < deg) {
                int s = csrs[beg + j];
                float e = as_[s * HH + hh] + ad;
                e = e > 0.f ? e : SLOPE * e;
                s_alpha[w][es][hh] = __expf(e - m) * invden;
                if (hh == 0) s_row[w][es] = s * (HC * 2);
            }
            #pragma unroll 2
            for (int jj = 0; jj < tl; jj += 2) {
                int j2 = jj + ep;
                int jc = j2 < tl ? j2 : jj;
                float a = j2 < tl ? s_alpha[w][jc][hsel] : 0.f;
                int ro = s_row[w][jc];
                const uint4 v = *reinterpret_cast<const uint4*>(hb + ro);
                acc[0] += a * bflo(v.x);
                acc[1] += a * bfhi(v.x);
                acc[2] += a * bflo(v.y);
                acc[3] += a * bfhi(v.y);
                acc[4] += a * bflo(v.z);
                acc[5] += a * bfhi(v.z);
                acc[6] += a * bflo(v.w);
                acc[7] += a * bfhi(v.w);
            }
        }
    }

    // ---- combine parity halves: lane keeps channels cl*8 + ep*4 + k ----
    float fin[4];
    #pragma unroll
    for (int k = 0; k < 4; ++k) {
        float send = ep ? acc[k] : acc[4 + k];        // half the partner stores
        float recv = __shfl_xor(send, 32, 64);
        fin[k] = (ep ? acc[4 + k] : acc[k]) + recv;
    }

    // ---- epilogue: bias + ELU + store (lane owns 4 channels) ----
    int ch = cl * 8 + ep * 4;
    const float4 b4 = *reinterpret_cast<const float4*>(bias + ch);
    float r0 = fin[0] + b4.x, r1 = fin[1] + b4.y, r2 = fin[2] + b4.z, r3 = fin[3] + b4.w;
    r0 = r0 > 0.f ? r0 : __expf(r0) - 1.f;
    r1 = r1 > 0.f ? r1 : __expf(r1) - 1.f;
    r2 = r2 > 0.f ? r2 : __expf(r2) - 1.f;
    r3 = r3 > 0.f ? r3 : __expf(r3) - 1.f;
    if constexpr (OUT_BF16) {
        uint2 q;
        q.x = (uint)f2bf(r0) | ((uint)f2bf(r1) << 16);
        q.y = (uint)f2bf(r2) | ((uint)f2bf(r3) << 16);
        *reinterpret_cast<uint2*>((ushort*)outp + (size_t)dst * HC + ch) = q;
    } else {
        *reinterpret_cast<float4*>((float*)outp + (size_t)dst * HC + ch) =
            make_float4(r0, r1, r2, r3);
    }
}

// ---------------- pooling (batch is sorted) ----------------

__global__ __launch_bounds__(256) void pool_kernel(const float* __restrict__ o,
                                                   const int* __restrict__ batch,
                                                   float* __restrict__ pool,
                                                   float* __restrict__ pcnt, int n) {
    int t = threadIdx.x;
    int start = blockIdx.x * 64;
    if (start >= n) return;
    int endn = min(start + 64, n);
    int g = batch[start];
    float acc = 0.f;
    int cnt = 0;
    for (int node = start; node < endn; ++node) {
        int gb = batch[node];
        if (gb != g) {
            atomicAdd(&pool[g * HC + t], acc);
            if (t == 0) atomicAdd(&pcnt[g], (float)cnt);
            acc = 0.f; cnt = 0; g = gb;
        }
        acc += o[(size_t)node * HC + t];
        cnt++;
    }
    atomicAdd(&pool[g * HC + t], acc);
    if (t == 0) atomicAdd(&pcnt[g], (float)cnt);
}

__global__ __launch_bounds__(256) void head_kernel(const float* __restrict__ pool,
                                                   const float* __restrict__ pcnt,
                                                   const float* __restrict__ Wl,
                                                   const float* __restrict__ bl,
                                                   float* __restrict__ out) {
    int g = blockIdx.x;
    int t = threadIdx.x;
    float inv = 1.f / fmaxf(pcnt[g], 1.f);
    float p = pool[g * HC + t] * inv;
    float v0 = p * Wl[t * 2 + 0];
    float v1 = p * Wl[t * 2 + 1];
    #pragma unroll
    for (int o = 32; o > 0; o >>= 1) {
        v0 += __shfl_down(v0, o, 64);
        v1 += __shfl_down(v1, o, 64);
    }
    __shared__ float s0[4], s1[4];
    int wid = t >> 6, lane = t & 63;
    if (lane == 0) { s0[wid] = v0; s1[wid] = v1; }
    __syncthreads();
    if (t == 0) {
        out[g * 2 + 0] = s0[0] + s0[1] + s0[2] + s0[3] + bl[0];
        out[g * 2 + 1] = s1[0] + s1[1] + s1[2] + s1[3] + bl[1];
    }
}

// ---------------- launch ----------------

extern "C" void kernel_launch(void* const* d_in, const int* in_sizes, int n_in,
                              void* d_out, int out_size, void* d_ws, size_t ws_size,
                              hipStream_t stream) {
    const float* x    = (const float*)d_in[0];
    const int*   ei   = (const int*)d_in[1];
    const int*   batch= (const int*)d_in[2];
    const float* W1   = (const float*)d_in[3];
    const float* as1  = (const float*)d_in[4];
    const float* ad1  = (const float*)d_in[5];
    const float* b1   = (const float*)d_in[6];
    const float* W2   = (const float*)d_in[7];
    const float* as2  = (const float*)d_in[8];
    const float* ad2  = (const float*)d_in[9];
    const float* b2   = (const float*)d_in[10];
    const float* Wl   = (const float*)d_in[11];
    const float* bl   = (const float*)d_in[12];
    float* out = (float*)d_out;

    char* ws = (char*)d_ws;
    size_t off_b = 0;
    auto alloc = [&](size_t bytes) -> void* {
        void* p = ws + off_b;
        off_b = (off_b + bytes + 255) & ~(size_t)255;
        return p;
    };
    ushort* h2   = (ushort*)alloc((size_t)NN * HC * 2);  // bf16 hidden (both layers)
    ushort* o1   = (ushort*)alloc((size_t)NN * HC * 2);  // bf16 layer-1 output
    float*  o2   = (float*)alloc((size_t)NN * HC * 4);   // fp32 layer-2 output
    float*  as_  = (float*)alloc((size_t)NN * HH * 4);
    float*  ad_  = (float*)alloc((size_t)NN * HH * 4);
    int*    deg  = (int*)alloc((size_t)NN * 4);
    int*    cur  = (int*)alloc((size_t)NN * 4);
    int*    offp = (int*)alloc((size_t)(NN + 1) * 4);
    int*    csrs = (int*)alloc((size_t)(EE + NN) * 4);
    float*  pool = (float*)alloc((size_t)GG * HC * 4);
    float*  pcnt = (float*)alloc((size_t)GG * 4);
    int*    bsum = (int*)alloc((size_t)64 * 4);
    ushort* Bt1  = (ushort*)alloc((size_t)HC * IN_CH * 2);
    ushort* Bt2  = (ushort*)alloc((size_t)HC * HC * 2);
    if (off_b > ws_size) return;

    const int NB = (NN + 1023) / 1024;

    // CSR by dst (shared by both layers)
    init_deg_kernel<<<(NN + 255) / 256, 256, 0, stream>>>(deg, NN);
    count_kernel<<<(EE + 255) / 256, 256, 0, stream>>>(ei, deg, EE);
    scanA_kernel<<<NB, 256, 0, stream>>>(deg, offp, bsum, NN);
    scanB_kernel<<<1, 64, 0, stream>>>(bsum, NB, offp + NN);
    scanC_kernel<<<(NN + 255) / 256, 256, 0, stream>>>(offp, cur, bsum, NN);
    scatter_kernel<<<(EE + NN + 255) / 256, 256, 0, stream>>>(ei, cur, csrs, EE, NN);

    // weight conversion (once per call)
    convert_w_kernel<<<dim3(IN_CH / 32, 8), 256, 0, stream>>>(W1, Bt1, IN_CH);
    convert_w_kernel<<<dim3(HC / 32, 8), 256, 0, stream>>>(W2, Bt2, HC);

    int gblocks = (NN + 63) / 64;
    int ablocks = (NN + 3) / 4;
    // Layer 1: GEMM(+alpha fused) -> aggregate (bf16 out)
    mfma_gemm_fused<IN_CH, false><<<gblocks, 256, 0, stream>>>(x, Bt1, h2, as_, ad_, as1, ad1, NN);
    aggregate6_kernel<true><<<ablocks, 256, 0, stream>>>(h2, as_, ad_, offp, csrs, b1, o1, NN);
    // Layer 2: GEMM(+alpha fused, bf16 A) -> aggregate (fp32 out)
    mfma_gemm_fused<HC, true><<<gblocks, 256, 0, stream>>>(o1, Bt2, h2, as_, ad_, as2, ad2, NN);
    aggregate6_kernel<false><<<ablocks, 256, 0, stream>>>(h2, as_, ad_, offp, csrs, b2, o2, NN);
    // Pool + classifier head
    hipMemsetAsync(pool, 0, (size_t)GG * HC * 4, stream);
    hipMemsetAsync(pcnt, 0, (size_t)GG * 4, stream);
    pool_kernel<<<(NN + 63) / 64, 256, 0, stream>>>(o2, batch, pool, pcnt, NN);
    head_kernel<<<GG, 256, 0, stream>>>(pool, pcnt, Wl, bl, out);
}